// Round 4
// baseline (55.812 us; speedup 1.0000x reference)
//
#include <hip/hip_runtime.h>

#define Bn 1024
#define Dn 32
#define Mn 8
#define Rn 4096
#define Cn 32
#define Kn 409     // int(0.1 * 4096)
#define NTH 512
#define RPT 8      // Rn / NTH
#define NBIN 1024
#define CCAP 256   // boundary-bin candidate cap

typedef unsigned int u32;

// Histogram bin of an f32 key; monotone non-decreasing. Keys are sums of
// negative exponents, typically in (-120, 0]; clamped outside.
__device__ __forceinline__ int binof(float kf) {
    int b = (int)floorf(kf * (float)(NBIN / 120.0) + (float)NBIN);
    return b < 0 ? 0 : (b > NBIN - 1 ? NBIN - 1 : b);
}

// Exact f64 sum in fixed dimension order d=0..31 (same order for every
// candidate -> consistent total order at the selection boundary).
__device__ __forceinline__ double rule_sum_f64(const uint4 q, const double* __restrict__ e) {
    double s = 0.0;
    const u32 wv[4] = {q.x, q.y, q.z, q.w};
#pragma unroll
    for (int p = 0; p < 16; ++p) {
        const u32 byte = (wv[p >> 2] >> (8 * (p & 3))) & 63u;
        s += e[(2 * p) * 8 + (byte & 7u)];
        s += e[(2 * p + 1) * 8 + (byte >> 3)];
    }
    return s;
}

// Fused prep: blocks [0,512) compute cons_sum; blocks [512,528) pack rules.
// Pack: byte p of the uint4 = m[2p] | (m[2p+1] << 3), p in [0,16).
__global__ __launch_bounds__(256) void prep_kernel(const float* __restrict__ cons,
                                                   const int* __restrict__ rules,
                                                   float* __restrict__ cons_out,
                                                   uint4* __restrict__ packed) {
    const int blk = blockIdx.x;
    const int t = threadIdx.x;
    if (blk < (Rn * Cn) / 256) {
        int idx = blk * 256 + t;
        int r = idx >> 5;
        int c = idx & 31;
        const float* p = cons + (size_t)r * (Dn + 1) * Cn + c;
        float s = 0.0f;
#pragma unroll
        for (int k = 0; k < Dn + 1; ++k) s += p[(size_t)k * Cn];
        cons_out[idx] = s;
    } else {
        int r = (blk - (Rn * Cn) / 256) * 256 + t;
        if (r >= Rn) return;
        const int* rp = rules + r * Dn;
        u32 w[4];
#pragma unroll
        for (int wi = 0; wi < 4; ++wi) {
            u32 v = 0;
#pragma unroll
            for (int j = 0; j < 4; ++j) {
                int p = wi * 4 + j;
                u32 m0 = (u32)rp[2 * p] & 7u;
                u32 m1 = (u32)rp[2 * p + 1] & 7u;
                v |= (m0 | (m1 << 3)) << (8 * j);
            }
            w[wi] = v;
        }
        packed[r] = make_uint4(w[0], w[1], w[2], w[3]);
    }
}

__global__ __launch_bounds__(NTH, 4) void anfis_kernel(
    const float* __restrict__ x,
    const float* __restrict__ centers,
    const float* __restrict__ widths,
    const uint4* __restrict__ rpack,
    const float* __restrict__ cons_sum,
    float* __restrict__ out_rule,
    float* __restrict__ out_norm,
    float* __restrict__ out_mask)
{
    __shared__ float  s_x[Dn];
    __shared__ double s_e[Dn * Mn];      // 2KB f64 single-dim table (boundary rescore)
    __shared__ u32    s_hist[NBIN];      // 4KB
    __shared__ int    s_wtot[8];
    __shared__ float  s_wsum[8];
    __shared__ int    s_cidx[CCAP];      // 1KB
    __shared__ double s_cval[CCAP];      // 2KB
    __shared__ int    s_cflag[CCAP];     // 1KB
    __shared__ int    s_selidx[Kn + 8];  // 1.6KB
    __shared__ float  s_selv[Kn + 8];    // 1.6KB
    __shared__ float  s_red[NTH];        // 2KB
    __shared__ int    s_bb, s_nab, s_ccnt;

    const int t = threadIdx.x;
    const int lane = t & 63;
    const int w = t >> 6;
    const int b = blockIdx.x;

    if (t < Dn) s_x[t] = x[b * Dn + t];
    if (t == 0) s_ccnt = 0;
    s_hist[t] = 0u;
    s_hist[t + NTH] = 0u;
    __syncthreads();

    // f64 single-dim table (LDS, used only for exact boundary rescore)
    if (t < Dn * Mn) {
        const int d = t >> 3;
        double dx = (double)s_x[d] - (double)centers[t];
        double ww = (double)widths[t];
        s_e[t] = -(dx * dx) / (2.0 * (ww * ww));
    }

    // Per-lane f32 e-table in registers: ereg[j] holds e[idx] for idx = j*64+lane.
    float ereg[4];
#pragma unroll
    for (int j = 0; j < 4; ++j) {
        const int idx = j * 64 + lane;
        const int d = idx >> 3;
        float dx = s_x[d] - centers[idx];
        float ww = widths[idx];
        ereg[j] = -(dx * dx) / (2.0f * ww * ww);
    }
    // Pair-table rows in registers: e2r[p][lane] = e[2p][lane&7] + e[2p+1][lane>>3].
    // Row p's source entries 16p+m0 and 16p+8+m1 live in ereg[p>>2] (no 64-crossing).
    float e2r[16];
#pragma unroll
    for (int p = 0; p < 16; ++p) {
        const int s0 = (16 * p) & 63;
        const int s1 = (16 * p + 8) & 63;
        e2r[p] = __shfl(ereg[p >> 2], s0 + (lane & 7)) +
                 __shfl(ereg[p >> 2], s1 + (lane >> 3));
    }

    // ---- phase 1: keys via conflict-free ds_bpermute gathers + histogram ----
    float kf[RPT];
#pragma unroll
    for (int i = 0; i < RPT; ++i) {
        const int r = i * NTH + t;
        const uint4 q = rpack[r];
        const u32 wv[4] = {q.x, q.y, q.z, q.w};
        float s = 0.f;
#pragma unroll
        for (int p = 0; p < 16; ++p) {
            const int byte = (int)((wv[p >> 2] >> (8 * (p & 3))) & 63u);
            s += __shfl(e2r[p], byte);
        }
        kf[i] = s;
        atomicAdd(&s_hist[binof(s)], 1u);
    }
    __syncthreads();

    // ---- suffix scan over 1024 bins: 2 bins/thread, shfl within wave ----
    const int h0 = (int)s_hist[2 * t];
    const int h1 = (int)s_hist[2 * t + 1];
    const int loc = h0 + h1;
    int S = loc;   // inclusive suffix within wave
#pragma unroll
    for (int off = 1; off < 64; off <<= 1) {
        int vv = __shfl(S, lane + off < 64 ? lane + off : lane);
        if (lane + off < 64) S += vv;
    }
    if (lane == 0) s_wtot[w] = S;
    __syncthreads();
    int wsuf = 0;
#pragma unroll
    for (int ww = 0; ww < 8; ++ww) wsuf += (ww > w) ? s_wtot[ww] : 0;
    {
        const int excl = (S - loc) + wsuf;  // count in bins > 2t+1
        const int vtot = excl + loc;        // count in bins >= 2t
        if (excl < Kn && vtot >= Kn) {
            int c = excl;
            if (c < Kn && c + h1 >= Kn) { s_bb = 2 * t + 1; s_nab = c; }
            c += h1;
            if (c < Kn && c + h0 >= Kn) { s_bb = 2 * t; s_nab = c; }
        }
    }
    __syncthreads();
    const int bb = s_bb;
    const int want_bin = Kn - s_nab;

    // ---- boundary-bin candidates: exact f64 rescore; owner remembers pos ----
    int mypos[RPT];
#pragma unroll
    for (int i = 0; i < RPT; ++i) {
        mypos[i] = -1;
        if (binof(kf[i]) == bb) {
            const int r = i * NTH + t;
            int pos = atomicAdd(&s_ccnt, 1);
            if (pos < CCAP) {
                mypos[i] = pos;
                s_cidx[pos] = r;
                s_cval[pos] = rule_sum_f64(rpack[r], s_e);
            }
        }
    }
    __syncthreads();
    const int cnt = s_ccnt < CCAP ? s_ccnt : CCAP;
    if (t < cnt) {
        const double mv = s_cval[t];
        const int mi = s_cidx[t];
        int rank = 0;
        for (int j = 0; j < cnt; ++j) {
            double ov = s_cval[j];
            int oi = s_cidx[j];
            rank += ((ov > mv) || (ov == mv && oi < mi)) ? 1 : 0;
        }
        s_cflag[t] = (rank < want_bin) ? 1 : 0;
    }
    __syncthreads();

    // ---- selection: expf once, kf[] becomes firing value ----
    u32 selbits = 0u;
    int cnt_sel = 0;
    float lsum = 0.f;
#pragma unroll
    for (int i = 0; i < RPT; ++i) {
        bool sel = (binof(kf[i]) > bb);
        if (mypos[i] >= 0) sel = (s_cflag[mypos[i]] != 0);
        float f = 0.f;
        if (sel) { f = expf(kf[i]); selbits |= (1u << i); ++cnt_sel; lsum += f; }
        kf[i] = f;
    }
    // wave reduce denom + wave prefix of selected-count (deterministic compaction)
#pragma unroll
    for (int off = 32; off >= 1; off >>= 1) lsum += __shfl_xor(lsum, off);
    if (lane == 0) s_wsum[w] = lsum;
    int p = cnt_sel;   // inclusive prefix within wave
#pragma unroll
    for (int off = 1; off < 64; off <<= 1) {
        int u = __shfl(p, lane >= off ? lane - off : lane);
        if (lane >= off) p += u;
    }
    if (lane == 63) s_wtot[w] = p;
    __syncthreads();
    float denom = 1e-9f;
#pragma unroll
    for (int ww = 0; ww < 8; ++ww) denom += s_wsum[ww];
    int base = 0;
#pragma unroll
    for (int ww = 0; ww < 8; ++ww) base += (ww < w) ? s_wtot[ww] : 0;
    int pos = base + (p - cnt_sel);

    // ---- fused normalize + writes + compaction ----
    float* onorm = out_norm + (size_t)b * Rn;
    float* omask = out_mask + (size_t)b * Rn;
#pragma unroll
    for (int i = 0; i < RPT; ++i) {
        const int r = i * NTH + t;
        const bool sel = (selbits >> i) & 1u;
        float nv = 0.f;
        if (sel) {
            nv = kf[i] / denom;
            s_selidx[pos] = r;
            s_selv[pos] = nv;
            ++pos;
        }
        onorm[r] = nv;
        omask[r] = sel ? 1.f : 0.f;
    }
    __syncthreads();

    // ---- sparse matvec ----
    const int g = t >> 5;      // 16 groups of 32
    const int c = t & 31;
    float acc = 0.f;
    for (int i = g; i < Kn; i += 16) {
        acc += s_selv[i] * cons_sum[s_selidx[i] * Cn + c];
    }
    s_red[t] = acc;
    __syncthreads();
    if (t < Cn) {
        float ss = 0.f;
#pragma unroll
        for (int gg = 0; gg < 16; ++gg) ss += s_red[gg * 32 + t];
        float xs = 1.f;
#pragma unroll
        for (int d = 0; d < Dn; ++d) xs += s_x[d];
        out_rule[b * Cn + t] = xs * ss;
    }
}

extern "C" void kernel_launch(void* const* d_in, const int* in_sizes, int n_in,
                              void* d_out, int out_size, void* d_ws, size_t ws_size,
                              hipStream_t stream) {
    (void)in_sizes; (void)n_in; (void)out_size; (void)ws_size;
    const float* x = (const float*)d_in[0];
    const float* centers = (const float*)d_in[1];
    const float* widths = (const float*)d_in[2];
    const float* consequents = (const float*)d_in[3];
    const int* rules = (const int*)d_in[4];

    float* out_rule = (float*)d_out;                       // B*C
    float* out_norm = out_rule + (size_t)Bn * Cn;          // B*R
    float* out_mask = out_norm + (size_t)Bn * Rn;          // B*R

    float* cons_sum = (float*)d_ws;                                            // R*C floats
    uint4* rpack = (uint4*)((char*)d_ws + (size_t)Rn * Cn * sizeof(float));    // R uint4

    const int prep_blocks = (Rn * Cn) / 256 + (Rn + 255) / 256;  // 512 + 16
    prep_kernel<<<prep_blocks, 256, 0, stream>>>(consequents, rules, cons_sum, rpack);
    anfis_kernel<<<Bn, NTH, 0, stream>>>(x, centers, widths, rpack, cons_sum,
                                         out_rule, out_norm, out_mask);
}

// Round 5
// 46.500 us; speedup vs baseline: 1.2003x; 1.2003x over previous
//
#include <hip/hip_runtime.h>

#define Bn 1024
#define Dn 32
#define Mn 8
#define Rn 4096
#define Cn 32
#define Kn 409     // int(0.1 * 4096)
#define NTH 512
#define RPT 8      // Rn / NTH
#define NBIN 1024
#define CCAP 256   // boundary-bin candidate cap (per row)

typedef unsigned int u32;

// Histogram bin of an f32 key; monotone non-decreasing. Keys are sums of
// negative exponents, typically in (-120, 0]; clamped outside.
__device__ __forceinline__ int binof(float kf) {
    int b = (int)floorf(kf * (float)(NBIN / 120.0) + (float)NBIN);
    return b < 0 ? 0 : (b > NBIN - 1 ? NBIN - 1 : b);
}

// Exact f64 sum in fixed dimension order d=0..31 (same order for every
// candidate -> consistent total order at the selection boundary).
__device__ __forceinline__ double rule_sum_f64(const uint4 q, const double* e) {
    double s = 0.0;
    const u32 wv[4] = {q.x, q.y, q.z, q.w};
#pragma unroll
    for (int p = 0; p < 16; ++p) {
        const u32 byte = (wv[p >> 2] >> (8 * (p & 3))) & 63u;
        s += e[(2 * p) * 8 + (byte & 7u)];
        s += e[(2 * p + 1) * 8 + (byte >> 3)];
    }
    return s;
}

// Fused prep: blocks [0,512) compute cons_sum; blocks [512,528) pack rules.
// Pack: byte p of the uint4 = m[2p] | (m[2p+1] << 3), p in [0,16).
__global__ __launch_bounds__(256) void prep_kernel(const float* __restrict__ cons,
                                                   const int* __restrict__ rules,
                                                   float* __restrict__ cons_out,
                                                   uint4* __restrict__ packed) {
    const int blk = blockIdx.x;
    const int t = threadIdx.x;
    if (blk < (Rn * Cn) / 256) {
        int idx = blk * 256 + t;
        int r = idx >> 5;
        int c = idx & 31;
        const float* p = cons + (size_t)r * (Dn + 1) * Cn + c;
        float s = 0.0f;
#pragma unroll
        for (int k = 0; k < Dn + 1; ++k) s += p[(size_t)k * Cn];
        cons_out[idx] = s;
    } else {
        int r = (blk - (Rn * Cn) / 256) * 256 + t;
        if (r >= Rn) return;
        const int* rp = rules + r * Dn;
        u32 w[4];
#pragma unroll
        for (int wi = 0; wi < 4; ++wi) {
            u32 v = 0;
#pragma unroll
            for (int j = 0; j < 4; ++j) {
                int p = wi * 4 + j;
                u32 m0 = (u32)rp[2 * p] & 7u;
                u32 m1 = (u32)rp[2 * p + 1] & 7u;
                v |= (m0 | (m1 << 3)) << (8 * j);
            }
            w[wi] = v;
        }
        packed[r] = make_uint4(w[0], w[1], w[2], w[3]);
    }
}

__global__ __launch_bounds__(NTH, 4) void anfis_kernel(
    const float* __restrict__ x,
    const float* __restrict__ centers,
    const float* __restrict__ widths,
    const uint4* __restrict__ rpack,
    const float* __restrict__ cons_sum,
    float* __restrict__ out_rule,
    float* __restrict__ out_norm,
    float* __restrict__ out_mask)
{
    __shared__ float2 s_p2[16 * 64];          // 8KB: interleaved 2-row pair table
    __shared__ float  s_ef[2 * 256];          // 2KB: f32 single-dim tables
    __shared__ double s_e[2 * 256];           // 4KB: f64 tables (boundary rescore)
    __shared__ u32    s_hist[2 * NBIN];       // 8KB
    __shared__ int    s_wtot[2][8];
    __shared__ float  s_wsum[2][8];
    __shared__ int    s_wpre[2][8];
    __shared__ int    s_cidx[2][CCAP];        // 2KB
    __shared__ double s_cval[2][CCAP];        // 4KB
    __shared__ int    s_cflag[2][CCAP];       // 2KB
    __shared__ int    s_selidx[2][Kn + 8];    // 3.3KB
    __shared__ float  s_selv[2][Kn + 8];      // 3.3KB
    __shared__ float  s_red[NTH];             // 2KB
    __shared__ float  s_x[2][Dn];
    __shared__ int    s_bb[2], s_nab[2], s_ccnt[2];

    const int t = threadIdx.x;
    const int lane = t & 63;
    const int w = t >> 6;
    const int b0 = blockIdx.x * 2;

    if (t < 2 * Dn) s_x[t >> 5][t & 31] = x[b0 * Dn + t];
    if (t < 2) s_ccnt[t] = 0;
    s_hist[t] = 0u; s_hist[t + NTH] = 0u;
    s_hist[t + 2 * NTH] = 0u; s_hist[t + 3 * NTH] = 0u;
    __syncthreads();

    // single-dim tables: 512 entries (row = t>>8, entry = t&255), 1/thread
    {
        const int row = t >> 8, e = t & 255, d = e >> 3;
        const float cf = centers[e];
        const float wf = widths[e];
        float dxf = s_x[row][d] - cf;
        s_ef[t] = -(dxf * dxf) / (2.0f * wf * wf);
        double dx = (double)s_x[row][d] - (double)cf;
        double ww = (double)wf;
        s_e[t] = -(dx * dx) / (2.0 * (ww * ww));
    }
    __syncthreads();

    // interleaved pair table: e2[p][c] = (row0, row1), c = m0 | m1<<3
#pragma unroll
    for (int k = 0; k < 2; ++k) {
        const int idx = k * NTH + t;   // [0, 1024)
        const int p = idx >> 6, c = idx & 63;
        const int i0 = (2 * p) * 8 + (c & 7);
        const int i1 = (2 * p + 1) * 8 + (c >> 3);
        s_p2[idx] = make_float2(s_ef[i0] + s_ef[i1], s_ef[256 + i0] + s_ef[256 + i1]);
    }
    __syncthreads();

    // ---- phase 1: one ds_read_b64 per gather serves both rows ----
    float kf[2][RPT];
#pragma unroll
    for (int i = 0; i < RPT; ++i) {
        const int r = i * NTH + t;
        const uint4 q = rpack[r];
        const u32 wv[4] = {q.x, q.y, q.z, q.w};
        float s0 = 0.f, s1 = 0.f;
#pragma unroll
        for (int p = 0; p < 16; ++p) {
            const int byte = (int)((wv[p >> 2] >> (8 * (p & 3))) & 63u);
            const float2 v = s_p2[(p << 6) + byte];
            s0 += v.x; s1 += v.y;
        }
        kf[0][i] = s0; kf[1][i] = s1;
        atomicAdd(&s_hist[binof(s0)], 1u);
        atomicAdd(&s_hist[NBIN + binof(s1)], 1u);
    }
    __syncthreads();

    // ---- suffix scans over both 1024-bin histograms ----
    int Sv[2], locv[2], h0v[2], h1v[2];
#pragma unroll
    for (int row = 0; row < 2; ++row) {
        h0v[row] = (int)s_hist[row * NBIN + 2 * t];
        h1v[row] = (int)s_hist[row * NBIN + 2 * t + 1];
        locv[row] = h0v[row] + h1v[row];
        int S = locv[row];
#pragma unroll
        for (int off = 1; off < 64; off <<= 1) {
            int vv = __shfl(S, lane + off < 64 ? lane + off : lane);
            if (lane + off < 64) S += vv;
        }
        Sv[row] = S;
        if (lane == 0) s_wtot[row][w] = S;
    }
    __syncthreads();
#pragma unroll
    for (int row = 0; row < 2; ++row) {
        int wsuf = 0;
#pragma unroll
        for (int ww = 0; ww < 8; ++ww) wsuf += (ww > w) ? s_wtot[row][ww] : 0;
        const int excl = (Sv[row] - locv[row]) + wsuf;  // bins > 2t+1
        const int vtot = excl + locv[row];              // bins >= 2t
        if (excl < Kn && vtot >= Kn) {
            int c = excl;
            if (c < Kn && c + h1v[row] >= Kn) { s_bb[row] = 2 * t + 1; s_nab[row] = c; }
            c += h1v[row];
            if (c < Kn && c + h0v[row] >= Kn) { s_bb[row] = 2 * t; s_nab[row] = c; }
        }
    }
    __syncthreads();

    // ---- boundary-bin candidates (exact f64 rescore), per row ----
    int mypos[2][RPT];
#pragma unroll
    for (int row = 0; row < 2; ++row) {
        const int bb = s_bb[row];
#pragma unroll
        for (int i = 0; i < RPT; ++i) {
            mypos[row][i] = -1;
            if (binof(kf[row][i]) == bb) {
                const int r = i * NTH + t;
                int pos = atomicAdd(&s_ccnt[row], 1);
                if (pos < CCAP) {
                    mypos[row][i] = pos;
                    s_cidx[row][pos] = r;
                    s_cval[row][pos] = rule_sum_f64(rpack[r], s_e + row * 256);
                }
            }
        }
    }
    __syncthreads();
    {
        const int cnt0 = s_ccnt[0] < CCAP ? s_ccnt[0] : CCAP;
        const int cnt1 = s_ccnt[1] < CCAP ? s_ccnt[1] : CCAP;
        int row = -1, idx = 0;
        if (t < cnt0) { row = 0; idx = t; }
        else if (t >= 256 && t - 256 < cnt1) { row = 1; idx = t - 256; }
        if (row >= 0) {
            const double mv = s_cval[row][idx];
            const int mi = s_cidx[row][idx];
            const int cnt = row ? cnt1 : cnt0;
            int rank = 0;
            for (int j = 0; j < cnt; ++j) {
                double ov = s_cval[row][j];
                int oi = s_cidx[row][j];
                rank += ((ov > mv) || (ov == mv && oi < mi)) ? 1 : 0;
            }
            s_cflag[row][idx] = (rank < Kn - s_nab[row]) ? 1 : 0;
        }
    }
    __syncthreads();

    // ---- selection + wave reductions (both rows), one barrier ----
    u32 selbits[2]; int cnt_sel[2]; int wexcl[2];
#pragma unroll
    for (int row = 0; row < 2; ++row) {
        const int bb = s_bb[row];
        u32 sb = 0; int cs = 0; float ls = 0.f;
#pragma unroll
        for (int i = 0; i < RPT; ++i) {
            bool sel = (binof(kf[row][i]) > bb);
            if (mypos[row][i] >= 0) sel = (s_cflag[row][mypos[row][i]] != 0);
            float f = 0.f;
            if (sel) { f = expf(kf[row][i]); sb |= (1u << i); ++cs; ls += f; }
            kf[row][i] = f;
        }
        selbits[row] = sb; cnt_sel[row] = cs;
#pragma unroll
        for (int off = 32; off >= 1; off >>= 1) ls += __shfl_xor(ls, off);
        if (lane == 0) s_wsum[row][w] = ls;
        int p = cs;
#pragma unroll
        for (int off = 1; off < 64; off <<= 1) {
            int u = __shfl(p, lane >= off ? lane - off : lane);
            if (lane >= off) p += u;
        }
        if (lane == 63) s_wpre[row][w] = p;
        wexcl[row] = p - cs;
    }
    __syncthreads();

    // ---- normalize + writes + compaction, per row ----
#pragma unroll
    for (int row = 0; row < 2; ++row) {
        float denom = 1e-9f;
#pragma unroll
        for (int ww = 0; ww < 8; ++ww) denom += s_wsum[row][ww];
        int base = 0;
#pragma unroll
        for (int ww = 0; ww < 8; ++ww) base += (ww < w) ? s_wpre[row][ww] : 0;
        int pos = base + wexcl[row];
        float* onorm = out_norm + (size_t)(b0 + row) * Rn;
        float* omask = out_mask + (size_t)(b0 + row) * Rn;
#pragma unroll
        for (int i = 0; i < RPT; ++i) {
            const int r = i * NTH + t;
            const bool sel = (selbits[row] >> i) & 1u;
            float nv = 0.f;
            if (sel) {
                nv = kf[row][i] / denom;
                s_selidx[row][pos] = r;
                s_selv[row][pos] = nv;
                ++pos;
            }
            onorm[r] = nv;
            omask[r] = sel ? 1.f : 0.f;
        }
    }
    __syncthreads();

    // ---- sparse matvec: waves 0-3 row0, waves 4-7 row1 ----
    {
        const int g = t >> 5;          // 0..15
        const int row = g >> 3;
        const int gi = g & 7;
        const int c = t & 31;
        float acc = 0.f;
        for (int i = gi; i < Kn; i += 8) {
            acc += s_selv[row][i] * cons_sum[s_selidx[row][i] * Cn + c];
        }
        s_red[t] = acc;
    }
    __syncthreads();
    if (t < 2 * Cn) {
        const int row = t >> 5, c = t & 31;
        float ss = 0.f;
#pragma unroll
        for (int gg = 0; gg < 8; ++gg) ss += s_red[(row * 8 + gg) * 32 + c];
        float xs = 1.f;
#pragma unroll
        for (int d = 0; d < Dn; ++d) xs += s_x[row][d];
        out_rule[(size_t)(b0 + row) * Cn + c] = xs * ss;
    }
}

extern "C" void kernel_launch(void* const* d_in, const int* in_sizes, int n_in,
                              void* d_out, int out_size, void* d_ws, size_t ws_size,
                              hipStream_t stream) {
    (void)in_sizes; (void)n_in; (void)out_size; (void)ws_size;
    const float* x = (const float*)d_in[0];
    const float* centers = (const float*)d_in[1];
    const float* widths = (const float*)d_in[2];
    const float* consequents = (const float*)d_in[3];
    const int* rules = (const int*)d_in[4];

    float* out_rule = (float*)d_out;                       // B*C
    float* out_norm = out_rule + (size_t)Bn * Cn;          // B*R
    float* out_mask = out_norm + (size_t)Bn * Rn;          // B*R

    float* cons_sum = (float*)d_ws;                                            // R*C floats
    uint4* rpack = (uint4*)((char*)d_ws + (size_t)Rn * Cn * sizeof(float));    // R uint4

    const int prep_blocks = (Rn * Cn) / 256 + (Rn + 255) / 256;  // 512 + 16
    prep_kernel<<<prep_blocks, 256, 0, stream>>>(consequents, rules, cons_sum, rpack);
    anfis_kernel<<<Bn / 2, NTH, 0, stream>>>(x, centers, widths, rpack, cons_sum,
                                             out_rule, out_norm, out_mask);
}